// Round 10
// baseline (199.042 us; speedup 1.0000x reference)
//
#include <hip/hip_runtime.h>

typedef __attribute__((ext_vector_type(8))) short bf16x8;
typedef __attribute__((ext_vector_type(4))) float f32x4;
typedef __attribute__((ext_vector_type(16))) float f32x16;
typedef __attribute__((ext_vector_type(4))) unsigned int u32x4;

#define DIMC 384
#define NHEADS 6
#define HDIM 64
#define BATCH 8
#define SEQ 2048
#define TOKENS (BATCH*SEQ)      /* 16384 */
#define QKV_OUT (3*DIMC)        /* 1152 */
#define VTP 2080                /* padded V^T row stride: 4160B = 65 x 64B, kills set-aliasing */

__device__ __forceinline__ unsigned short f2bf(float f) {
  unsigned int u = __float_as_uint(f);
  u += 0x7fffu + ((u >> 16) & 1u);
  return (unsigned short)(u >> 16);
}

__device__ __forceinline__ unsigned int cvt_pk_bf16(float a, float b) {
  unsigned int r;
  asm volatile("v_cvt_pk_bf16_f32 %0, %1, %2" : "=v"(r) : "v"(a), "v"(b));
  return r;
}

__device__ __forceinline__ void async_load16(const void* g, void* l) {
  __builtin_amdgcn_global_load_lds(
      (const __attribute__((address_space(1))) unsigned int*)g,
      (__attribute__((address_space(3))) unsigned int*)l, 16, 0, 0);
}

// ---------------- merged cast fp32 -> bf16 (x, qkv_w, proj_w in one launch) ----------------
#define N4_X   (TOKENS*DIMC/4)
#define N4_W1  (QKV_OUT*DIMC/4)
#define N4_W2  (DIMC*DIMC/4)
__global__ void cast3_kernel(const float* __restrict__ x,
                             const float* __restrict__ w1,
                             const float* __restrict__ w2,
                             unsigned short* __restrict__ ox,
                             unsigned short* __restrict__ o1,
                             unsigned short* __restrict__ o2) {
  int i = blockIdx.x * blockDim.x + threadIdx.x;
  const int stride = gridDim.x * blockDim.x;
  for (; i < N4_X + N4_W1 + N4_W2; i += stride) {
    const float* src; unsigned short* dst; int j = i;
    if (j < N4_X)            { src = x;  dst = ox; }
    else if (j < N4_X+N4_W1) { j -= N4_X; src = w1; dst = o1; }
    else                     { j -= N4_X+N4_W1; src = w2; dst = o2; }
    float4 v = ((const float4*)src)[j];
    ushort4 o;
    o.x = f2bf(v.x); o.y = f2bf(v.y); o.z = f2bf(v.z); o.w = f2bf(v.w);
    ((ushort4*)dst)[j] = o;
  }
}

// ---------------- QKV GEMM (dbuf pipeline): [16384,384] x [1152,384]^T + bias -> Q,K,Vt ----
__global__ __launch_bounds__(256) void qkv_gemm_kernel(
    const unsigned short* __restrict__ A,   // x bf16 [16384][384]
    const unsigned short* __restrict__ W,   // qkv_w bf16 [1152][384]
    const float* __restrict__ bias,         // [1152]
    unsigned short* __restrict__ Qb,        // [48][2048][64]
    unsigned short* __restrict__ Kb,        // [48][2048][64]
    unsigned short* __restrict__ Vtb) {     // [48][64][VTP]  (transposed, padded!)
  __shared__ unsigned short As[2][128*32];
  __shared__ unsigned short Bs[2][128*32];
  const int tid = threadIdx.x;
  const int w = tid >> 6, l = tid & 63;
  const int wm = w >> 1, wn = w & 1;
  const int q4 = l >> 4, r15 = l & 15;
  const int m0 = blockIdx.y * 128;
  const int n0 = blockIdx.x * 128;

  f32x4 acc[4][4];
#pragma unroll
  for (int i = 0; i < 4; i++)
#pragma unroll
    for (int j = 0; j < 4; j++) acc[i][j] = f32x4{0.f, 0.f, 0.f, 0.f};

  const int arow = l >> 2;            // 0..15 within wave
  const int achk = l & 3;
  const unsigned short* Asrc = A + (size_t)(m0 + w*16 + arow) * 384 + achk * 8;
  const unsigned short* Wsrc = W + (size_t)(n0 + w*16 + arow) * 384 + achk * 8;

#pragma unroll
  for (int cc = 0; cc < 2; ++cc) {
    async_load16(Asrc + cc*64*384, (char*)As[0] + cc*4096 + w*1024);
    async_load16(Wsrc + cc*64*384, (char*)Bs[0] + cc*4096 + w*1024);
  }

  for (int kt = 0; kt < 12; ++kt) {
    const int buf = kt & 1;
    if (kt < 11) {
#pragma unroll
      for (int cc = 0; cc < 2; ++cc) {
        async_load16(Asrc + (kt+1)*32 + cc*64*384, (char*)As[buf^1] + cc*4096 + w*1024);
        async_load16(Wsrc + (kt+1)*32 + cc*64*384, (char*)Bs[buf^1] + cc*4096 + w*1024);
      }
      asm volatile("s_waitcnt vmcnt(4)" ::: "memory");
    } else {
      asm volatile("s_waitcnt vmcnt(0)" ::: "memory");
    }
    __builtin_amdgcn_s_barrier();
    asm volatile("" ::: "memory");
    bf16x8 a[4], b[4];
#pragma unroll
    for (int mi = 0; mi < 4; mi++)
      a[mi] = *(const bf16x8*)(&As[buf][(wm*64 + mi*16 + r15)*32 + q4*8]);
#pragma unroll
    for (int ni = 0; ni < 4; ni++)
      b[ni] = *(const bf16x8*)(&Bs[buf][(wn*64 + ni*16 + r15)*32 + q4*8]);
    __builtin_amdgcn_s_setprio(1);
#pragma unroll
    for (int mi = 0; mi < 4; mi++)
#pragma unroll
      for (int ni = 0; ni < 4; ni++)
        acc[mi][ni] = __builtin_amdgcn_mfma_f32_16x16x32_bf16(
            a[mi], b[ni], acc[mi][ni], 0, 0, 0);
    __builtin_amdgcn_s_setprio(0);
    asm volatile("s_waitcnt lgkmcnt(0)" ::: "memory");
    __builtin_amdgcn_s_barrier();
    asm volatile("" ::: "memory");
  }
  const int c3 = blockIdx.x / 3;
  const int nrel0 = (blockIdx.x % 3) * 128 + wn * 64;
  if (c3 == 2) {
#pragma unroll
    for (int ni = 0; ni < 4; ni++) {
      int ncol = nrel0 + ni*16 + r15;
      float bv = bias[n0 + wn*64 + ni*16 + r15];
      int h = ncol >> 6, d = ncol & 63;
#pragma unroll
      for (int mi = 0; mi < 4; mi++) {
        int m = m0 + wm*64 + mi*16 + 4*q4;
        int bb = m >> 11, t = m & 2047;
        ushort4 pk;
        pk.x = f2bf(acc[mi][ni][0] + bv);
        pk.y = f2bf(acc[mi][ni][1] + bv);
        pk.z = f2bf(acc[mi][ni][2] + bv);
        pk.w = f2bf(acc[mi][ni][3] + bv);
        *(ushort4*)(Vtb + ((size_t)(bb*NHEADS + h)*HDIM + d)*VTP + t) = pk;
      }
    }
  } else {
    unsigned short* D = (c3 == 0) ? Qb : Kb;
    const float scale = (c3 == 0) ? 0.125f * 1.4426950408889634f : 1.0f;
#pragma unroll
    for (int ni = 0; ni < 4; ni++) {
      int ncol = nrel0 + ni*16 + r15;
      float bv = bias[n0 + wn*64 + ni*16 + r15];
      int h = ncol >> 6, d = ncol & 63;
#pragma unroll
      for (int mi = 0; mi < 4; mi++) {
#pragma unroll
        for (int reg = 0; reg < 4; reg++) {
          int m = m0 + wm*64 + mi*16 + 4*q4 + reg;
          int bb = m >> 11, t = m & 2047;
          float v = (acc[mi][ni][reg] + bv) * scale;
          D[((size_t)(bb*NHEADS + h)*SEQ + t)*HDIM + d] = f2bf(v);
        }
      }
    }
  }
}

// ---- flash attention: NO LDS — direct-from-L2 K/V fragment loads, bare barrier only ----
__global__ __launch_bounds__(256, 3) void flash_kernel(
    const unsigned short* __restrict__ Q, const unsigned short* __restrict__ K,
    const unsigned short* __restrict__ Vt, unsigned short* __restrict__ O2) {
  const int tid = threadIdx.x;
  const int w = tid >> 6, l = tid & 63;
  const int hl = l >> 5, l31 = l & 31;
  // XCD-aware swizzle: 768 blocks, 96 per XCD -> each bh (512KB K+V) pinned to one XCD L2
  const int wg = blockIdx.x;
  const int logical = (wg & 7) * 96 + (wg >> 3);
  const int qt = logical & 15, bh = logical >> 4;
  const unsigned short* Qp = Q  + (size_t)bh * SEQ * HDIM;
  const unsigned short* Kp = K  + (size_t)bh * SEQ * HDIM;
  const unsigned short* Vp = Vt + (size_t)bh * HDIM * VTP;

  // Q fragments (B-operand): qf[ks] = Q[qrow][ks*16 + hl*8 .. +7]
  const int qrow = qt*128 + w*32 + l31;
  bf16x8 qf[4];
#pragma unroll
  for (int ks = 0; ks < 4; ks++)
    qf[ks] = *(const bf16x8*)(Qp + (size_t)qrow*HDIM + ks*16 + hl*8);

  // per-lane base pointers for K (A-op) and V^T (B-op) fragment runs
  const unsigned short* krow0 = Kp + (size_t)l31*HDIM      + hl*8;   // key = l31
  const unsigned short* krow1 = Kp + (size_t)(32+l31)*HDIM + hl*8;   // key = 32+l31
  const unsigned short* vrow0 = Vp + (size_t)l31*VTP      + hl*8;    // d = l31
  const unsigned short* vrow1 = Vp + (size_t)(32+l31)*VTP + hl*8;    // d = 32+l31

  f32x16 o0 = {}, o1 = {};
  float l_run = 0.f;

  for (int kt = 0; kt < 32; ++kt) {
    const size_t koff = (size_t)kt*64*HDIM;
    const size_t voff = (size_t)kt*64;

    // K fragments for this tile (dies after QK — low pressure)
    bf16x8 kf0[4], kf1[4];
#pragma unroll
    for (int ks = 0; ks < 4; ks++) {
      kf0[ks] = *(const bf16x8*)(krow0 + koff + ks*16);
      kf1[ks] = *(const bf16x8*)(krow1 + koff + ks*16);
    }

    // S^T = K . Q^T : D[m=key][n=q]; lane: q=l31, key=(reg&3)+8*(reg>>2)+4*hl (+32*kb)
    f32x16 s0 = {}, s1 = {};
    __builtin_amdgcn_s_setprio(1);
#pragma unroll
    for (int ks = 0; ks < 4; ks++) {
      s0 = __builtin_amdgcn_mfma_f32_32x32x16_bf16(kf0[ks], qf[ks], s0, 0, 0, 0);
      s1 = __builtin_amdgcn_mfma_f32_32x32x16_bf16(kf1[ks], qf[ks], s1, 0, 0, 0);
    }
    __builtin_amdgcn_s_setprio(0);

    // issue V fragment loads now — softmax below covers their L1/L2 latency
    bf16x8 vf0[4], vf1[4];
#pragma unroll
    for (int ks = 0; ks < 4; ks++) {
      vf0[ks] = *(const bf16x8*)(vrow0 + voff + ks*16);
      vf1[ks] = *(const bf16x8*)(vrow1 + voff + ks*16);
    }

    // softmax, no max subtraction: |s| hard-bounded (<4) in log2 domain
    unsigned int Y[2][4][2];
    float lsum = 0.f;
#pragma unroll
    for (int h = 0; h < 4; h++) {
      float a0 = __builtin_amdgcn_exp2f(s0[4*h+0]);
      float a1 = __builtin_amdgcn_exp2f(s0[4*h+1]);
      float a2 = __builtin_amdgcn_exp2f(s0[4*h+2]);
      float a3 = __builtin_amdgcn_exp2f(s0[4*h+3]);
      lsum += (a0+a1)+(a2+a3);
      Y[0][h][0] = cvt_pk_bf16(a0, a1);
      Y[0][h][1] = cvt_pk_bf16(a2, a3);
      float b0 = __builtin_amdgcn_exp2f(s1[4*h+0]);
      float b1 = __builtin_amdgcn_exp2f(s1[4*h+1]);
      float b2 = __builtin_amdgcn_exp2f(s1[4*h+2]);
      float b3 = __builtin_amdgcn_exp2f(s1[4*h+3]);
      lsum += (b0+b1)+(b2+b3);
      Y[1][h][0] = cvt_pk_bf16(b0, b1);
      Y[1][h][1] = cvt_pk_bf16(b2, b3);
    }
    l_run += lsum;

    // P -> A-fragments entirely in-register via permlane32_swap
    bf16x8 pa[4];
#pragma unroll
    for (int ksl = 0; ksl < 4; ksl++) {
      const int kb = ksl >> 1, P2 = ksl & 1;
      unsigned int x0 = Y[kb][2*P2+0][0], x1 = Y[kb][2*P2+0][1];
      unsigned int y0 = Y[kb][2*P2+1][0], y1 = Y[kb][2*P2+1][1];
      asm volatile("v_permlane32_swap_b32 %0, %1" : "+v"(x0), "+v"(y0));
      asm volatile("v_permlane32_swap_b32 %0, %1" : "+v"(x1), "+v"(y1));
      u32x4 t; t[0] = x0; t[1] = x1; t[2] = y0; t[3] = y1;
      union { u32x4 u; bf16x8 b; } cvt; cvt.u = t;
      pa[ksl] = cvt.b;
    }

    // O += P @ V : D[m=q][n=d]
    __builtin_amdgcn_s_setprio(1);
#pragma unroll
    for (int ksl = 0; ksl < 4; ksl++) {
      o0 = __builtin_amdgcn_mfma_f32_32x32x16_bf16(pa[ksl], vf0[ksl], o0, 0, 0, 0);
      o1 = __builtin_amdgcn_mfma_f32_32x32x16_bf16(pa[ksl], vf1[ksl], o1, 0, 0, 0);
    }
    __builtin_amdgcn_s_setprio(0);

    // bare execution barrier (no waitcnt): keeps 4 waves on the same tile for L1 reuse
    __builtin_amdgcn_s_barrier();
  }

  // epilogue: finish l over key-halves, normalize, store
  l_run += __shfl_xor(l_run, 32, 64);
  const float linv = 1.0f / l_run;
  const int b = bh / NHEADS, h = bh % NHEADS;
#pragma unroll
  for (int reg = 0; reg < 16; reg++) {
    const int qr = (reg & 3) + 8*(reg >> 2) + 4*hl;
    const float lr = __shfl(linv, qr, 64);
    const int t = qt*128 + w*32 + qr;
    unsigned short* dst = O2 + ((size_t)(b*SEQ + t))*DIMC + h*HDIM;
    dst[l31]      = f2bf(o0[reg] * lr);
    dst[32 + l31] = f2bf(o1[reg] * lr);
  }
}

// ---------------- proj GEMM (dbuf, BN=64): [16384,384] x [384,384]^T + bias -> fp32 ------
__global__ __launch_bounds__(256) void proj_gemm_kernel(
    const unsigned short* __restrict__ A,
    const unsigned short* __restrict__ W,
    const float* __restrict__ bias,
    float* __restrict__ out) {
  __shared__ unsigned short As[2][128*32];
  __shared__ unsigned short Bs[2][64*32];
  const int tid = threadIdx.x;
  const int w = tid >> 6, l = tid & 63;
  const int q4 = l >> 4, r15 = l & 15;
  const int m0 = blockIdx.y * 128;
  const int n0 = blockIdx.x * 64;

  f32x4 acc[2][4];
#pragma unroll
  for (int i = 0; i < 2; i++)
#pragma unroll
    for (int j = 0; j < 4; j++) acc[i][j] = f32x4{0.f, 0.f, 0.f, 0.f};

  const int arow = l >> 2;
  const int achk = l & 3;
  const unsigned short* Asrc = A + (size_t)(m0 + w*16 + arow) * 384 + achk * 8;
  const unsigned short* Wsrc = W + (size_t)(n0 + w*16 + arow) * 384 + achk * 8;

#pragma unroll
  for (int cc = 0; cc < 2; ++cc)
    async_load16(Asrc + cc*64*384, (char*)As[0] + cc*4096 + w*1024);
  async_load16(Wsrc, (char*)Bs[0] + w*1024);

  for (int kt = 0; kt < 12; ++kt) {
    const int buf = kt & 1;
    if (kt < 11) {
#pragma unroll
      for (int cc = 0; cc < 2; ++cc)
        async_load16(Asrc + (kt+1)*32 + cc*64*384, (char*)As[buf^1] + cc*4096 + w*1024);
      async_load16(Wsrc + (kt+1)*32, (char*)Bs[buf^1] + w*1024);
      asm volatile("s_waitcnt vmcnt(3)" ::: "memory");
    } else {
      asm volatile("s_waitcnt vmcnt(0)" ::: "memory");
    }
    __builtin_amdgcn_s_barrier();
    asm volatile("" ::: "memory");
    bf16x8 a[2], b[4];
#pragma unroll
    for (int mi = 0; mi < 2; mi++)
      a[mi] = *(const bf16x8*)(&As[buf][(w*32 + mi*16 + r15)*32 + q4*8]);
#pragma unroll
    for (int ni = 0; ni < 4; ni++)
      b[ni] = *(const bf16x8*)(&Bs[buf][(ni*16 + r15)*32 + q4*8]);
    __builtin_amdgcn_s_setprio(1);
#pragma unroll
    for (int mi = 0; mi < 2; mi++)
#pragma unroll
      for (int ni = 0; ni < 4; ni++)
        acc[mi][ni] = __builtin_amdgcn_mfma_f32_16x16x32_bf16(
            a[mi], b[ni], acc[mi][ni], 0, 0, 0);
    __builtin_amdgcn_s_setprio(0);
    asm volatile("s_waitcnt lgkmcnt(0)" ::: "memory");
    __builtin_amdgcn_s_barrier();
    asm volatile("" ::: "memory");
  }
#pragma unroll
  for (int ni = 0; ni < 4; ni++) {
    int ncol = n0 + ni*16 + r15;
    float bv = bias[ncol];
#pragma unroll
    for (int mi = 0; mi < 2; mi++) {
#pragma unroll
      for (int reg = 0; reg < 4; reg++) {
        int m = m0 + w*32 + mi*16 + 4*q4 + reg;
        out[(size_t)m * DIMC + ncol] = acc[mi][ni][reg] + bv;
      }
    }
  }
}

extern "C" void kernel_launch(void* const* d_in, const int* in_sizes, int n_in,
                              void* d_out, int out_size, void* d_ws, size_t ws_size,
                              hipStream_t stream) {
  const float* x      = (const float*)d_in[0];
  const float* qkv_w  = (const float*)d_in[1];
  const float* qkv_b  = (const float*)d_in[2];
  const float* proj_w = (const float*)d_in[3];
  const float* proj_b = (const float*)d_in[4];
  float* out = (float*)d_out;

  unsigned short* xbf   = (unsigned short*)d_ws;
  unsigned short* wqkv  = xbf   + (size_t)TOKENS * DIMC;
  unsigned short* wproj = wqkv  + (size_t)QKV_OUT * DIMC;
  unsigned short* Qb    = wproj + (size_t)DIMC * DIMC;
  unsigned short* Kb    = Qb    + (size_t)TOKENS * DIMC;
  unsigned short* Vtb   = Kb    + (size_t)TOKENS * DIMC;           // [48][64][VTP]
  unsigned short* A2    = Vtb   + (size_t)48 * HDIM * VTP;

  cast3_kernel<<<2048, 256, 0, stream>>>(x, qkv_w, proj_w, xbf, wqkv, wproj);
  qkv_gemm_kernel<<<dim3(9, 128), 256, 0, stream>>>(xbf, wqkv, qkv_b, Qb, Kb, Vtb);
  flash_kernel<<<768, 256, 0, stream>>>(Qb, Kb, Vtb, A2);
  proj_gemm_kernel<<<dim3(6, 128), 256, 0, stream>>>(A2, wproj, proj_b, out);
}

// Round 11
// 124.068 us; speedup vs baseline: 1.6043x; 1.6043x over previous
//
#include <hip/hip_runtime.h>

typedef __attribute__((ext_vector_type(8))) short bf16x8;
typedef __attribute__((ext_vector_type(4))) float f32x4;
typedef __attribute__((ext_vector_type(16))) float f32x16;
typedef __attribute__((ext_vector_type(4))) unsigned int u32x4;

#define DIMC 384
#define NHEADS 6
#define HDIM 64
#define BATCH 8
#define SEQ 2048
#define TOKENS (BATCH*SEQ)      /* 16384 */
#define QKV_OUT (3*DIMC)        /* 1152 */

__device__ __forceinline__ unsigned short f2bf(float f) {
  unsigned int u = __float_as_uint(f);
  u += 0x7fffu + ((u >> 16) & 1u);
  return (unsigned short)(u >> 16);
}

__device__ __forceinline__ unsigned int cvt_pk_bf16(float a, float b) {
  unsigned int r;
  asm volatile("v_cvt_pk_bf16_f32 %0, %1, %2" : "=v"(r) : "v"(a), "v"(b));
  return r;
}

__device__ __forceinline__ void async_load16(const void* g, void* l) {
  __builtin_amdgcn_global_load_lds(
      (const __attribute__((address_space(1))) unsigned int*)g,
      (__attribute__((address_space(3))) unsigned int*)l, 16, 0, 0);
}

// ---------------- merged cast fp32 -> bf16 (x, qkv_w, proj_w in one launch) ----------------
#define N4_X   (TOKENS*DIMC/4)
#define N4_W1  (QKV_OUT*DIMC/4)
#define N4_W2  (DIMC*DIMC/4)
__global__ void cast3_kernel(const float* __restrict__ x,
                             const float* __restrict__ w1,
                             const float* __restrict__ w2,
                             unsigned short* __restrict__ ox,
                             unsigned short* __restrict__ o1,
                             unsigned short* __restrict__ o2) {
  int i = blockIdx.x * blockDim.x + threadIdx.x;
  const int stride = gridDim.x * blockDim.x;
  for (; i < N4_X + N4_W1 + N4_W2; i += stride) {
    const float* src; unsigned short* dst; int j = i;
    if (j < N4_X)            { src = x;  dst = ox; }
    else if (j < N4_X+N4_W1) { j -= N4_X; src = w1; dst = o1; }
    else                     { j -= N4_X+N4_W1; src = w2; dst = o2; }
    float4 v = ((const float4*)src)[j];
    ushort4 o;
    o.x = f2bf(v.x); o.y = f2bf(v.y); o.z = f2bf(v.z); o.w = f2bf(v.w);
    ((ushort4*)dst)[j] = o;
  }
}

// ------- QKV GEMM (3-buffer, 1 barrier/iter): [16384,384] x [1152,384]^T + bias -> Q,K,Vt --
__global__ __launch_bounds__(256) void qkv_gemm_kernel(
    const unsigned short* __restrict__ A,   // x bf16 [16384][384]
    const unsigned short* __restrict__ W,   // qkv_w bf16 [1152][384]
    const float* __restrict__ bias,         // [1152]
    unsigned short* __restrict__ Qb,        // [48][2048][64]
    unsigned short* __restrict__ Kb,        // [48][2048][64]
    unsigned short* __restrict__ Vtb) {     // [48][64][2048]  (transposed!)
  __shared__ unsigned short As[3][128*32];
  __shared__ unsigned short Bs[3][128*32];
  const int tid = threadIdx.x;
  const int w = tid >> 6, l = tid & 63;
  const int wm = w >> 1, wn = w & 1;
  const int q4 = l >> 4, r15 = l & 15;
  const int m0 = blockIdx.y * 128;
  const int n0 = blockIdx.x * 128;

  f32x4 acc[4][4];
#pragma unroll
  for (int i = 0; i < 4; i++)
#pragma unroll
    for (int j = 0; j < 4; j++) acc[i][j] = f32x4{0.f, 0.f, 0.f, 0.f};

  const int arow = l >> 2;            // 0..15 within wave
  const int achk = l & 3;
  const unsigned short* Asrc = A + (size_t)(m0 + w*16 + arow) * 384 + achk * 8;
  const unsigned short* Wsrc = W + (size_t)(n0 + w*16 + arow) * 384 + achk * 8;

  // prologue: stage tile 0 into buf 0
#pragma unroll
  for (int cc = 0; cc < 2; ++cc) {
    async_load16(Asrc + cc*64*384, (char*)&As[0][0] + cc*4096 + w*1024);
    async_load16(Wsrc + cc*64*384, (char*)&Bs[0][0] + cc*4096 + w*1024);
  }

  int cur = 0;
  for (int kt = 0; kt < 12; ++kt) {
    const int nxt = (cur == 2) ? 0 : cur + 1;
    if (kt < 11) {
#pragma unroll
      for (int cc = 0; cc < 2; ++cc) {
        async_load16(Asrc + (kt+1)*32 + cc*64*384, (char*)&As[0][0] + nxt*8192 + cc*4096 + w*1024);
        async_load16(Wsrc + (kt+1)*32 + cc*64*384, (char*)&Bs[0][0] + nxt*8192 + cc*4096 + w*1024);
      }
      asm volatile("s_waitcnt vmcnt(4)" ::: "memory");
    } else {
      asm volatile("s_waitcnt vmcnt(0)" ::: "memory");
    }
    __builtin_amdgcn_s_barrier();
    asm volatile("" ::: "memory");
    const unsigned short* asb = &As[0][0] + cur*4096;
    const unsigned short* bsb = &Bs[0][0] + cur*4096;
    bf16x8 a[4], b[4];
#pragma unroll
    for (int mi = 0; mi < 4; mi++)
      a[mi] = *(const bf16x8*)(asb + (wm*64 + mi*16 + r15)*32 + q4*8);
#pragma unroll
    for (int ni = 0; ni < 4; ni++)
      b[ni] = *(const bf16x8*)(bsb + (wn*64 + ni*16 + r15)*32 + q4*8);
    __builtin_amdgcn_s_setprio(1);
#pragma unroll
    for (int mi = 0; mi < 4; mi++)
#pragma unroll
      for (int ni = 0; ni < 4; ni++)
        acc[mi][ni] = __builtin_amdgcn_mfma_f32_16x16x32_bf16(
            a[mi], b[ni], acc[mi][ni], 0, 0, 0);
    __builtin_amdgcn_s_setprio(0);
    cur = nxt;
  }
  const int c3 = blockIdx.x / 3;
  const int nrel0 = (blockIdx.x % 3) * 128 + wn * 64;
  if (c3 == 2) {
#pragma unroll
    for (int ni = 0; ni < 4; ni++) {
      int ncol = nrel0 + ni*16 + r15;
      float bv = bias[n0 + wn*64 + ni*16 + r15];
      int h = ncol >> 6, d = ncol & 63;
#pragma unroll
      for (int mi = 0; mi < 4; mi++) {
        int m = m0 + wm*64 + mi*16 + 4*q4;
        int bb = m >> 11, t = m & 2047;
        ushort4 pk;
        pk.x = f2bf(acc[mi][ni][0] + bv);
        pk.y = f2bf(acc[mi][ni][1] + bv);
        pk.z = f2bf(acc[mi][ni][2] + bv);
        pk.w = f2bf(acc[mi][ni][3] + bv);
        *(ushort4*)(Vtb + ((size_t)(bb*NHEADS + h)*HDIM + d)*SEQ + t) = pk;
      }
    }
  } else {
    unsigned short* D = (c3 == 0) ? Qb : Kb;
    const float scale = (c3 == 0) ? 0.125f * 1.4426950408889634f : 1.0f;
#pragma unroll
    for (int ni = 0; ni < 4; ni++) {
      int ncol = nrel0 + ni*16 + r15;
      float bv = bias[n0 + wn*64 + ni*16 + r15];
      int h = ncol >> 6, d = ncol & 63;
#pragma unroll
      for (int mi = 0; mi < 4; mi++) {
#pragma unroll
        for (int reg = 0; reg < 4; reg++) {
          int m = m0 + wm*64 + mi*16 + 4*q4 + reg;
          int bb = m >> 11, t = m & 2047;
          float v = (acc[mi][ni][reg] + bv) * scale;
          D[((size_t)(bb*NHEADS + h)*SEQ + t)*HDIM + d] = f2bf(v);
        }
      }
    }
  }
}

// ---- flash attention: R8 body, 3-buffer LDS, ONE barrier/iter, no LDS drain ----
__global__ __launch_bounds__(256, 3) void flash_kernel(
    const unsigned short* __restrict__ Q, const unsigned short* __restrict__ K,
    const unsigned short* __restrict__ Vt, unsigned short* __restrict__ O2) {
  __shared__ unsigned short Ks[3][64*64];   // [key][dk], swizzled
  __shared__ unsigned short Vs[3][64*64];   // V^T [d][key], swizzled
  const int tid = threadIdx.x;
  const int w = tid >> 6, l = tid & 63;
  const int hl = l >> 5, l31 = l & 31, l7 = l & 7;
  // XCD-aware swizzle: 768 blocks, 96 per XCD -> each bh entirely on one XCD
  const int wg = blockIdx.x;
  const int logical = (wg & 7) * 96 + (wg >> 3);
  const int qt = logical & 15, bh = logical >> 4;
  const unsigned short* Qp = Q  + (size_t)bh * SEQ * HDIM;
  const unsigned short* Kp = K  + (size_t)bh * SEQ * HDIM;
  const unsigned short* Vp = Vt + (size_t)bh * HDIM * SEQ;

  // Q fragments (B-operand): qf[ks] = Q[qrow][ks*16 + hl*8 .. +7]
  const int qrow = qt*128 + w*32 + l31;
  bf16x8 qf[4];
#pragma unroll
  for (int ks = 0; ks < 4; ks++)
    qf[ks] = *(const bf16x8*)(Qp + (size_t)qrow*HDIM + ks*16 + hl*8);

  // staging: linear LDS dest; pre-swizzled global chunk = pos ^ (row&7) ^ octave(w)
  const int srow = w*8 + (l >> 3);
  const int sch  = l7 ^ (l >> 3) ^ w;
  const unsigned short* Ksrc = Kp + (size_t)srow*HDIM + sch*8;
  const unsigned short* Vsrc = Vp + (size_t)srow*SEQ  + sch*8;

  // ds_read byte offsets: row=l31, pos = (ks*2+hl) ^ (row&7) ^ ((row>>3)&3)
  const int swl = (l31 >> 3) & 3;
  int rdoff[4];
#pragma unroll
  for (int ks = 0; ks < 4; ks++)
    rdoff[ks] = l31*128 + (((ks*2 + hl) ^ l7 ^ swl) << 4);

  f32x16 o0 = {}, o1 = {};
  float l_run = 0.f;

  // prologue: stage tile 0 -> buf 0
  async_load16(Ksrc,           (char*)&Ks[0][0] + w*1024);
  async_load16(Ksrc + 32*HDIM, (char*)&Ks[0][0] + w*1024 + 4096);
  async_load16(Vsrc,           (char*)&Vs[0][0] + w*1024);
  async_load16(Vsrc + 32*SEQ,  (char*)&Vs[0][0] + w*1024 + 4096);

  int cur = 0;
  for (int kt = 0; kt < 32; ++kt) {
    const int nxt = (cur == 2) ? 0 : cur + 1;
    if (kt < 31) {
      const unsigned short* ks_ = Ksrc + (size_t)(kt+1)*64*HDIM;
      const unsigned short* vs_ = Vsrc + (size_t)(kt+1)*64;
      char* kd = (char*)&Ks[0][0] + nxt*8192 + w*1024;
      char* vd = (char*)&Vs[0][0] + nxt*8192 + w*1024;
      async_load16(ks_,           kd);
      async_load16(ks_ + 32*HDIM, kd + 4096);
      async_load16(vs_,           vd);
      async_load16(vs_ + 32*SEQ,  vd + 4096);
      asm volatile("s_waitcnt vmcnt(4)" ::: "memory");  // own tile-kt loads done
    } else {
      asm volatile("s_waitcnt vmcnt(0)" ::: "memory");
    }
    __builtin_amdgcn_s_barrier();       // single barrier: tile kt fully in LDS
    asm volatile("" ::: "memory");

    const char* ksb = (const char*)&Ks[0][0] + cur*8192;
    const char* vsb = (const char*)&Vs[0][0] + cur*8192;

    // S^T = K . Q^T : D[m=key][n=q], lane: q=l31, key=(reg&3)+8*(reg>>2)+4*hl (+32*kb)
    f32x16 s0 = {}, s1 = {};
    __builtin_amdgcn_s_setprio(1);
#pragma unroll
    for (int ks = 0; ks < 4; ks++) {
      bf16x8 kf0 = *(const bf16x8*)(ksb + rdoff[ks]);
      bf16x8 kf1 = *(const bf16x8*)(ksb + 4096 + rdoff[ks]);
      s0 = __builtin_amdgcn_mfma_f32_32x32x16_bf16(kf0, qf[ks], s0, 0, 0, 0);
      s1 = __builtin_amdgcn_mfma_f32_32x32x16_bf16(kf1, qf[ks], s1, 0, 0, 0);
    }
    __builtin_amdgcn_s_setprio(0);

    // softmax, no max subtraction: |s| hard-bounded (<4) in log2 domain
    unsigned int Y[2][4][2];
    float lsum = 0.f;
#pragma unroll
    for (int h = 0; h < 4; h++) {
      float a0 = __builtin_amdgcn_exp2f(s0[4*h+0]);
      float a1 = __builtin_amdgcn_exp2f(s0[4*h+1]);
      float a2 = __builtin_amdgcn_exp2f(s0[4*h+2]);
      float a3 = __builtin_amdgcn_exp2f(s0[4*h+3]);
      lsum += (a0+a1)+(a2+a3);
      Y[0][h][0] = cvt_pk_bf16(a0, a1);
      Y[0][h][1] = cvt_pk_bf16(a2, a3);
      float b0 = __builtin_amdgcn_exp2f(s1[4*h+0]);
      float b1 = __builtin_amdgcn_exp2f(s1[4*h+1]);
      float b2 = __builtin_amdgcn_exp2f(s1[4*h+2]);
      float b3 = __builtin_amdgcn_exp2f(s1[4*h+3]);
      lsum += (b0+b1)+(b2+b3);
      Y[1][h][0] = cvt_pk_bf16(b0, b1);
      Y[1][h][1] = cvt_pk_bf16(b2, b3);
    }
    l_run += lsum;

    // P -> A-fragments entirely in-register via permlane32_swap
    bf16x8 pa[4];
#pragma unroll
    for (int ksl = 0; ksl < 4; ksl++) {
      const int kb = ksl >> 1, P2 = ksl & 1;
      unsigned int x0 = Y[kb][2*P2+0][0], x1 = Y[kb][2*P2+0][1];
      unsigned int y0 = Y[kb][2*P2+1][0], y1 = Y[kb][2*P2+1][1];
      asm volatile("v_permlane32_swap_b32 %0, %1" : "+v"(x0), "+v"(y0));
      asm volatile("v_permlane32_swap_b32 %0, %1" : "+v"(x1), "+v"(y1));
      u32x4 t; t[0] = x0; t[1] = x1; t[2] = y0; t[3] = y1;
      union { u32x4 u; bf16x8 b; } cvt; cvt.u = t;
      pa[ksl] = cvt.b;
    }

    // O += P @ V : D[m=q][n=d]
    __builtin_amdgcn_s_setprio(1);
#pragma unroll
    for (int ksl = 0; ksl < 4; ksl++) {
      bf16x8 vf0 = *(const bf16x8*)(vsb + rdoff[ksl]);
      bf16x8 vf1 = *(const bf16x8*)(vsb + 4096 + rdoff[ksl]);
      o0 = __builtin_amdgcn_mfma_f32_32x32x16_bf16(pa[ksl], vf0, o0, 0, 0, 0);
      o1 = __builtin_amdgcn_mfma_f32_32x32x16_bf16(pa[ksl], vf1, o1, 0, 0, 0);
    }
    __builtin_amdgcn_s_setprio(0);
    cur = nxt;   // no bottom barrier, no lgkmcnt drain (3-buffer safety)
  }

  // epilogue: finish l over key-halves, normalize, store
  l_run += __shfl_xor(l_run, 32, 64);
  const float linv = 1.0f / l_run;
  const int b = bh / NHEADS, h = bh % NHEADS;
#pragma unroll
  for (int reg = 0; reg < 16; reg++) {
    const int qr = (reg & 3) + 8*(reg >> 2) + 4*hl;
    const float lr = __shfl(linv, qr, 64);
    const int t = qt*128 + w*32 + qr;
    unsigned short* dst = O2 + ((size_t)(b*SEQ + t))*DIMC + h*HDIM;
    dst[l31]      = f2bf(o0[reg] * lr);
    dst[32 + l31] = f2bf(o1[reg] * lr);
  }
}

// ---------------- proj GEMM (dbuf, BN=64, unchanged control): -> fp32 out ------
__global__ __launch_bounds__(256) void proj_gemm_kernel(
    const unsigned short* __restrict__ A,
    const unsigned short* __restrict__ W,
    const float* __restrict__ bias,
    float* __restrict__ out) {
  __shared__ unsigned short As[2][128*32];
  __shared__ unsigned short Bs[2][64*32];
  const int tid = threadIdx.x;
  const int w = tid >> 6, l = tid & 63;
  const int q4 = l >> 4, r15 = l & 15;
  const int m0 = blockIdx.y * 128;
  const int n0 = blockIdx.x * 64;

  f32x4 acc[2][4];
#pragma unroll
  for (int i = 0; i < 2; i++)
#pragma unroll
    for (int j = 0; j < 4; j++) acc[i][j] = f32x4{0.f, 0.f, 0.f, 0.f};

  const int arow = l >> 2;
  const int achk = l & 3;
  const unsigned short* Asrc = A + (size_t)(m0 + w*16 + arow) * 384 + achk * 8;
  const unsigned short* Wsrc = W + (size_t)(n0 + w*16 + arow) * 384 + achk * 8;

#pragma unroll
  for (int cc = 0; cc < 2; ++cc)
    async_load16(Asrc + cc*64*384, (char*)As[0] + cc*4096 + w*1024);
  async_load16(Wsrc, (char*)Bs[0] + w*1024);

  for (int kt = 0; kt < 12; ++kt) {
    const int buf = kt & 1;
    if (kt < 11) {
#pragma unroll
      for (int cc = 0; cc < 2; ++cc)
        async_load16(Asrc + (kt+1)*32 + cc*64*384, (char*)As[buf^1] + cc*4096 + w*1024);
      async_load16(Wsrc + (kt+1)*32, (char*)Bs[buf^1] + w*1024);
      asm volatile("s_waitcnt vmcnt(3)" ::: "memory");
    } else {
      asm volatile("s_waitcnt vmcnt(0)" ::: "memory");
    }
    __builtin_amdgcn_s_barrier();
    asm volatile("" ::: "memory");
    bf16x8 a[2], b[4];
#pragma unroll
    for (int mi = 0; mi < 2; mi++)
      a[mi] = *(const bf16x8*)(&As[buf][(w*32 + mi*16 + r15)*32 + q4*8]);
#pragma unroll
    for (int ni = 0; ni < 4; ni++)
      b[ni] = *(const bf16x8*)(&Bs[buf][(ni*16 + r15)*32 + q4*8]);
    __builtin_amdgcn_s_setprio(1);
#pragma unroll
    for (int mi = 0; mi < 2; mi++)
#pragma unroll
      for (int ni = 0; ni < 4; ni++)
        acc[mi][ni] = __builtin_amdgcn_mfma_f32_16x16x32_bf16(
            a[mi], b[ni], acc[mi][ni], 0, 0, 0);
    __builtin_amdgcn_s_setprio(0);
    asm volatile("s_waitcnt lgkmcnt(0)" ::: "memory");
    __builtin_amdgcn_s_barrier();
    asm volatile("" ::: "memory");
  }
#pragma unroll
  for (int ni = 0; ni < 4; ni++) {
    int ncol = n0 + ni*16 + r15;
    float bv = bias[ncol];
#pragma unroll
    for (int mi = 0; mi < 2; mi++) {
#pragma unroll
      for (int reg = 0; reg < 4; reg++) {
        int m = m0 + w*32 + mi*16 + 4*q4 + reg;
        out[(size_t)m * DIMC + ncol] = acc[mi][ni][reg] + bv;
      }
    }
  }
}

extern "C" void kernel_launch(void* const* d_in, const int* in_sizes, int n_in,
                              void* d_out, int out_size, void* d_ws, size_t ws_size,
                              hipStream_t stream) {
  const float* x      = (const float*)d_in[0];
  const float* qkv_w  = (const float*)d_in[1];
  const float* qkv_b  = (const float*)d_in[2];
  const float* proj_w = (const float*)d_in[3];
  const float* proj_b = (const float*)d_in[4];
  float* out = (float*)d_out;

  unsigned short* xbf   = (unsigned short*)d_ws;
  unsigned short* wqkv  = xbf   + (size_t)TOKENS * DIMC;
  unsigned short* wproj = wqkv  + (size_t)QKV_OUT * DIMC;
  unsigned short* Qb    = wproj + (size_t)DIMC * DIMC;
  unsigned short* Kb    = Qb    + (size_t)TOKENS * DIMC;
  unsigned short* Vtb   = Kb    + (size_t)TOKENS * DIMC;
  unsigned short* A2    = Vtb   + (size_t)TOKENS * DIMC;

  cast3_kernel<<<2048, 256, 0, stream>>>(x, qkv_w, proj_w, xbf, wqkv, wproj);
  qkv_gemm_kernel<<<dim3(9, 128), 256, 0, stream>>>(xbf, wqkv, qkv_b, Qb, Kb, Vtb);
  flash_kernel<<<768, 256, 0, stream>>>(Qb, Kb, Vtb, A2);
  proj_gemm_kernel<<<dim3(6, 128), 256, 0, stream>>>(A2, wproj, proj_b, out);
}

// Round 12
// 122.821 us; speedup vs baseline: 1.6206x; 1.0102x over previous
//
#include <hip/hip_runtime.h>

typedef __attribute__((ext_vector_type(8))) short bf16x8;
typedef __attribute__((ext_vector_type(4))) float f32x4;
typedef __attribute__((ext_vector_type(16))) float f32x16;
typedef __attribute__((ext_vector_type(4))) unsigned int u32x4;

#define DIMC 384
#define NHEADS 6
#define HDIM 64
#define BATCH 8
#define SEQ 2048
#define TOKENS (BATCH*SEQ)      /* 16384 */
#define QKV_OUT (3*DIMC)        /* 1152 */

__device__ __forceinline__ unsigned short f2bf(float f) {
  unsigned int u = __float_as_uint(f);
  u += 0x7fffu + ((u >> 16) & 1u);
  return (unsigned short)(u >> 16);
}

__device__ __forceinline__ unsigned int cvt_pk_bf16(float a, float b) {
  unsigned int r;
  asm volatile("v_cvt_pk_bf16_f32 %0, %1, %2" : "=v"(r) : "v"(a), "v"(b));
  return r;
}

__device__ __forceinline__ void async_load16(const void* g, void* l) {
  __builtin_amdgcn_global_load_lds(
      (const __attribute__((address_space(1))) unsigned int*)g,
      (__attribute__((address_space(3))) unsigned int*)l, 16, 0, 0);
}

// ---------------- merged cast fp32 -> bf16 (x, qkv_w, proj_w in one launch) ----------------
#define N4_X   (TOKENS*DIMC/4)
#define N4_W1  (QKV_OUT*DIMC/4)
#define N4_W2  (DIMC*DIMC/4)
__global__ void cast3_kernel(const float* __restrict__ x,
                             const float* __restrict__ w1,
                             const float* __restrict__ w2,
                             unsigned short* __restrict__ ox,
                             unsigned short* __restrict__ o1,
                             unsigned short* __restrict__ o2) {
  int i = blockIdx.x * blockDim.x + threadIdx.x;
  const int stride = gridDim.x * blockDim.x;
  for (; i < N4_X + N4_W1 + N4_W2; i += stride) {
    const float* src; unsigned short* dst; int j = i;
    if (j < N4_X)            { src = x;  dst = ox; }
    else if (j < N4_X+N4_W1) { j -= N4_X; src = w1; dst = o1; }
    else                     { j -= N4_X+N4_W1; src = w2; dst = o2; }
    float4 v = ((const float4*)src)[j];
    ushort4 o;
    o.x = f2bf(v.x); o.y = f2bf(v.y); o.z = f2bf(v.z); o.w = f2bf(v.w);
    ((ushort4*)dst)[j] = o;
  }
}

// ------- QKV GEMM (3-buffer, 1 barrier/iter): [16384,384] x [1152,384]^T + bias -> Q,K,Vt --
__global__ __launch_bounds__(256) void qkv_gemm_kernel(
    const unsigned short* __restrict__ A,   // x bf16 [16384][384]
    const unsigned short* __restrict__ W,   // qkv_w bf16 [1152][384]
    const float* __restrict__ bias,         // [1152]
    unsigned short* __restrict__ Qb,        // [48][2048][64]
    unsigned short* __restrict__ Kb,        // [48][2048][64]
    unsigned short* __restrict__ Vtb) {     // [48][64][2048]  (transposed!)
  __shared__ unsigned short As[3][128*32];
  __shared__ unsigned short Bs[3][128*32];
  const int tid = threadIdx.x;
  const int w = tid >> 6, l = tid & 63;
  const int wm = w >> 1, wn = w & 1;
  const int q4 = l >> 4, r15 = l & 15;
  const int m0 = blockIdx.y * 128;
  const int n0 = blockIdx.x * 128;

  f32x4 acc[4][4];
#pragma unroll
  for (int i = 0; i < 4; i++)
#pragma unroll
    for (int j = 0; j < 4; j++) acc[i][j] = f32x4{0.f, 0.f, 0.f, 0.f};

  const int arow = l >> 2;            // 0..15 within wave
  const int achk = l & 3;
  const unsigned short* Asrc = A + (size_t)(m0 + w*16 + arow) * 384 + achk * 8;
  const unsigned short* Wsrc = W + (size_t)(n0 + w*16 + arow) * 384 + achk * 8;

  // prologue: stage tile 0 into buf 0
#pragma unroll
  for (int cc = 0; cc < 2; ++cc) {
    async_load16(Asrc + cc*64*384, (char*)&As[0][0] + cc*4096 + w*1024);
    async_load16(Wsrc + cc*64*384, (char*)&Bs[0][0] + cc*4096 + w*1024);
  }

  int cur = 0;
  for (int kt = 0; kt < 12; ++kt) {
    const int nxt = (cur == 2) ? 0 : cur + 1;
    if (kt < 11) {
#pragma unroll
      for (int cc = 0; cc < 2; ++cc) {
        async_load16(Asrc + (kt+1)*32 + cc*64*384, (char*)&As[0][0] + nxt*8192 + cc*4096 + w*1024);
        async_load16(Wsrc + (kt+1)*32 + cc*64*384, (char*)&Bs[0][0] + nxt*8192 + cc*4096 + w*1024);
      }
      asm volatile("s_waitcnt vmcnt(4)" ::: "memory");
    } else {
      asm volatile("s_waitcnt vmcnt(0)" ::: "memory");
    }
    __builtin_amdgcn_s_barrier();
    asm volatile("" ::: "memory");
    const unsigned short* asb = &As[0][0] + cur*4096;
    const unsigned short* bsb = &Bs[0][0] + cur*4096;
    bf16x8 a[4], b[4];
#pragma unroll
    for (int mi = 0; mi < 4; mi++)
      a[mi] = *(const bf16x8*)(asb + (wm*64 + mi*16 + r15)*32 + q4*8);
#pragma unroll
    for (int ni = 0; ni < 4; ni++)
      b[ni] = *(const bf16x8*)(bsb + (wn*64 + ni*16 + r15)*32 + q4*8);
    __builtin_amdgcn_s_setprio(1);
#pragma unroll
    for (int mi = 0; mi < 4; mi++)
#pragma unroll
      for (int ni = 0; ni < 4; ni++)
        acc[mi][ni] = __builtin_amdgcn_mfma_f32_16x16x32_bf16(
            a[mi], b[ni], acc[mi][ni], 0, 0, 0);
    __builtin_amdgcn_s_setprio(0);
    cur = nxt;
  }
  const int c3 = blockIdx.x / 3;
  const int nrel0 = (blockIdx.x % 3) * 128 + wn * 64;
  if (c3 == 2) {
#pragma unroll
    for (int ni = 0; ni < 4; ni++) {
      int ncol = nrel0 + ni*16 + r15;
      float bv = bias[n0 + wn*64 + ni*16 + r15];
      int h = ncol >> 6, d = ncol & 63;
#pragma unroll
      for (int mi = 0; mi < 4; mi++) {
        int m = m0 + wm*64 + mi*16 + 4*q4;
        int bb = m >> 11, t = m & 2047;
        ushort4 pk;
        pk.x = f2bf(acc[mi][ni][0] + bv);
        pk.y = f2bf(acc[mi][ni][1] + bv);
        pk.z = f2bf(acc[mi][ni][2] + bv);
        pk.w = f2bf(acc[mi][ni][3] + bv);
        *(ushort4*)(Vtb + ((size_t)(bb*NHEADS + h)*HDIM + d)*SEQ + t) = pk;
      }
    }
  } else {
    unsigned short* D = (c3 == 0) ? Qb : Kb;
    const float scale = (c3 == 0) ? 0.125f * 1.4426950408889634f : 1.0f;
#pragma unroll
    for (int ni = 0; ni < 4; ni++) {
      int ncol = nrel0 + ni*16 + r15;
      float bv = bias[n0 + wn*64 + ni*16 + r15];
      int h = ncol >> 6, d = ncol & 63;
#pragma unroll
      for (int mi = 0; mi < 4; mi++) {
#pragma unroll
        for (int reg = 0; reg < 4; reg++) {
          int m = m0 + wm*64 + mi*16 + 4*q4 + reg;
          int bb = m >> 11, t = m & 2047;
          float v = (acc[mi][ni][reg] + bv) * scale;
          D[((size_t)(bb*NHEADS + h)*SEQ + t)*HDIM + d] = f2bf(v);
        }
      }
    }
  }
}

// ---- flash attention: 3-buffer, 1 barrier/iter, PHASE-SPLIT softmax (low reg pressure) ----
__global__ __launch_bounds__(256, 3) void flash_kernel(
    const unsigned short* __restrict__ Q, const unsigned short* __restrict__ K,
    const unsigned short* __restrict__ Vt, unsigned short* __restrict__ O2) {
  __shared__ unsigned short Ks[3][64*64];   // [key][dk], swizzled
  __shared__ unsigned short Vs[3][64*64];   // V^T [d][key], swizzled
  const int tid = threadIdx.x;
  const int w = tid >> 6, l = tid & 63;
  const int hl = l >> 5, l31 = l & 31, l7 = l & 7;
  // XCD-aware swizzle: 768 blocks, 96 per XCD -> each bh entirely on one XCD
  const int wg = blockIdx.x;
  const int logical = (wg & 7) * 96 + (wg >> 3);
  const int qt = logical & 15, bh = logical >> 4;
  const unsigned short* Qp = Q  + (size_t)bh * SEQ * HDIM;
  const unsigned short* Kp = K  + (size_t)bh * SEQ * HDIM;
  const unsigned short* Vp = Vt + (size_t)bh * HDIM * SEQ;

  // Q fragments (B-operand): qf[ks] = Q[qrow][ks*16 + hl*8 .. +7]
  const int qrow = qt*128 + w*32 + l31;
  bf16x8 qf[4];
#pragma unroll
  for (int ks = 0; ks < 4; ks++)
    qf[ks] = *(const bf16x8*)(Qp + (size_t)qrow*HDIM + ks*16 + hl*8);

  // staging: linear LDS dest; pre-swizzled global chunk = pos ^ (row&7) ^ octave(w)
  const int srow = w*8 + (l >> 3);
  const int sch  = l7 ^ (l >> 3) ^ w;
  const unsigned short* Ksrc = Kp + (size_t)srow*HDIM + sch*8;
  const unsigned short* Vsrc = Vp + (size_t)srow*SEQ  + sch*8;

  // ds_read byte offsets: row=l31, pos = (ks*2+hl) ^ (row&7) ^ ((row>>3)&3)
  const int swl = (l31 >> 3) & 3;
  int rdoff[4];
#pragma unroll
  for (int ks = 0; ks < 4; ks++)
    rdoff[ks] = l31*128 + (((ks*2 + hl) ^ l7 ^ swl) << 4);

  f32x16 o0 = {}, o1 = {};
  float l_run = 0.f;

  // prologue: stage tile 0 -> buf 0
  async_load16(Ksrc,           (char*)&Ks[0][0] + w*1024);
  async_load16(Ksrc + 32*HDIM, (char*)&Ks[0][0] + w*1024 + 4096);
  async_load16(Vsrc,           (char*)&Vs[0][0] + w*1024);
  async_load16(Vsrc + 32*SEQ,  (char*)&Vs[0][0] + w*1024 + 4096);

  int cur = 0;
  for (int kt = 0; kt < 32; ++kt) {
    const int nxt = (cur == 2) ? 0 : cur + 1;
    if (kt < 31) {
      const unsigned short* ks_ = Ksrc + (size_t)(kt+1)*64*HDIM;
      const unsigned short* vs_ = Vsrc + (size_t)(kt+1)*64;
      char* kd = (char*)&Ks[0][0] + nxt*8192 + w*1024;
      char* vd = (char*)&Vs[0][0] + nxt*8192 + w*1024;
      async_load16(ks_,           kd);
      async_load16(ks_ + 32*HDIM, kd + 4096);
      async_load16(vs_,           vd);
      async_load16(vs_ + 32*SEQ,  vd + 4096);
      asm volatile("s_waitcnt vmcnt(4)" ::: "memory");  // own tile-kt loads done
    } else {
      asm volatile("s_waitcnt vmcnt(0)" ::: "memory");
    }
    __builtin_amdgcn_s_barrier();       // single barrier: tile kt fully in LDS
    asm volatile("" ::: "memory");

    const char* ksb = (const char*)&Ks[0][0] + cur*8192;
    const char* vsb = (const char*)&Vs[0][0] + cur*8192;

    // ---- phase A: key-half 0 (keys 0-31): QK, exp2, pack; s + Y0 die before phase B ----
    bf16x8 pa0, pa1;
    float lsumA;
    {
      f32x16 s = {};
      __builtin_amdgcn_s_setprio(1);
#pragma unroll
      for (int ks = 0; ks < 4; ks++) {
        bf16x8 kf = *(const bf16x8*)(ksb + rdoff[ks]);
        s = __builtin_amdgcn_mfma_f32_32x32x16_bf16(kf, qf[ks], s, 0, 0, 0);
      }
      __builtin_amdgcn_s_setprio(0);
      unsigned int Y[4][2];
      float lsum = 0.f;
#pragma unroll
      for (int h = 0; h < 4; h++) {
        float a0 = __builtin_amdgcn_exp2f(s[4*h+0]);
        float a1 = __builtin_amdgcn_exp2f(s[4*h+1]);
        float a2 = __builtin_amdgcn_exp2f(s[4*h+2]);
        float a3 = __builtin_amdgcn_exp2f(s[4*h+3]);
        lsum += (a0+a1)+(a2+a3);
        Y[h][0] = cvt_pk_bf16(a0, a1);
        Y[h][1] = cvt_pk_bf16(a2, a3);
      }
      lsumA = lsum;
      {
        unsigned int x0 = Y[0][0], x1 = Y[0][1], y0 = Y[1][0], y1 = Y[1][1];
        asm volatile("v_permlane32_swap_b32 %0, %1" : "+v"(x0), "+v"(y0));
        asm volatile("v_permlane32_swap_b32 %0, %1" : "+v"(x1), "+v"(y1));
        u32x4 t; t[0] = x0; t[1] = x1; t[2] = y0; t[3] = y1;
        union { u32x4 u; bf16x8 b; } cvt; cvt.u = t;
        pa0 = cvt.b;
      }
      {
        unsigned int x0 = Y[2][0], x1 = Y[2][1], y0 = Y[3][0], y1 = Y[3][1];
        asm volatile("v_permlane32_swap_b32 %0, %1" : "+v"(x0), "+v"(y0));
        asm volatile("v_permlane32_swap_b32 %0, %1" : "+v"(x1), "+v"(y1));
        u32x4 t; t[0] = x0; t[1] = x1; t[2] = y0; t[3] = y1;
        union { u32x4 u; bf16x8 b; } cvt; cvt.u = t;
        pa1 = cvt.b;
      }
    }
    __builtin_amdgcn_sched_barrier(0);   // keep phase B from hoisting into A

    // ---- phase B: key-half 1 (keys 32-63): reuses the same accumulator registers ----
    bf16x8 pa2, pa3;
    float lsumB;
    {
      f32x16 s = {};
      __builtin_amdgcn_s_setprio(1);
#pragma unroll
      for (int ks = 0; ks < 4; ks++) {
        bf16x8 kf = *(const bf16x8*)(ksb + 4096 + rdoff[ks]);
        s = __builtin_amdgcn_mfma_f32_32x32x16_bf16(kf, qf[ks], s, 0, 0, 0);
      }
      __builtin_amdgcn_s_setprio(0);
      unsigned int Y[4][2];
      float lsum = 0.f;
#pragma unroll
      for (int h = 0; h < 4; h++) {
        float a0 = __builtin_amdgcn_exp2f(s[4*h+0]);
        float a1 = __builtin_amdgcn_exp2f(s[4*h+1]);
        float a2 = __builtin_amdgcn_exp2f(s[4*h+2]);
        float a3 = __builtin_amdgcn_exp2f(s[4*h+3]);
        lsum += (a0+a1)+(a2+a3);
        Y[h][0] = cvt_pk_bf16(a0, a1);
        Y[h][1] = cvt_pk_bf16(a2, a3);
      }
      lsumB = lsum;
      {
        unsigned int x0 = Y[0][0], x1 = Y[0][1], y0 = Y[1][0], y1 = Y[1][1];
        asm volatile("v_permlane32_swap_b32 %0, %1" : "+v"(x0), "+v"(y0));
        asm volatile("v_permlane32_swap_b32 %0, %1" : "+v"(x1), "+v"(y1));
        u32x4 t; t[0] = x0; t[1] = x1; t[2] = y0; t[3] = y1;
        union { u32x4 u; bf16x8 b; } cvt; cvt.u = t;
        pa2 = cvt.b;
      }
      {
        unsigned int x0 = Y[2][0], x1 = Y[2][1], y0 = Y[3][0], y1 = Y[3][1];
        asm volatile("v_permlane32_swap_b32 %0, %1" : "+v"(x0), "+v"(y0));
        asm volatile("v_permlane32_swap_b32 %0, %1" : "+v"(x1), "+v"(y1));
        u32x4 t; t[0] = x0; t[1] = x1; t[2] = y0; t[3] = y1;
        union { u32x4 u; bf16x8 b; } cvt; cvt.u = t;
        pa3 = cvt.b;
      }
    }
    l_run += lsumA + lsumB;
    __builtin_amdgcn_sched_barrier(0);   // keep PV reads from hoisting into B

    // ---- phase C: O += P @ V : D[m=q][n=d] ----
    __builtin_amdgcn_s_setprio(1);
    {
      bf16x8 vf0 = *(const bf16x8*)(vsb + rdoff[0]);
      bf16x8 vf1 = *(const bf16x8*)(vsb + 4096 + rdoff[0]);
      o0 = __builtin_amdgcn_mfma_f32_32x32x16_bf16(pa0, vf0, o0, 0, 0, 0);
      o1 = __builtin_amdgcn_mfma_f32_32x32x16_bf16(pa0, vf1, o1, 0, 0, 0);
      vf0 = *(const bf16x8*)(vsb + rdoff[1]);
      vf1 = *(const bf16x8*)(vsb + 4096 + rdoff[1]);
      o0 = __builtin_amdgcn_mfma_f32_32x32x16_bf16(pa1, vf0, o0, 0, 0, 0);
      o1 = __builtin_amdgcn_mfma_f32_32x32x16_bf16(pa1, vf1, o1, 0, 0, 0);
      vf0 = *(const bf16x8*)(vsb + rdoff[2]);
      vf1 = *(const bf16x8*)(vsb + 4096 + rdoff[2]);
      o0 = __builtin_amdgcn_mfma_f32_32x32x16_bf16(pa2, vf0, o0, 0, 0, 0);
      o1 = __builtin_amdgcn_mfma_f32_32x32x16_bf16(pa2, vf1, o1, 0, 0, 0);
      vf0 = *(const bf16x8*)(vsb + rdoff[3]);
      vf1 = *(const bf16x8*)(vsb + 4096 + rdoff[3]);
      o0 = __builtin_amdgcn_mfma_f32_32x32x16_bf16(pa3, vf0, o0, 0, 0, 0);
      o1 = __builtin_amdgcn_mfma_f32_32x32x16_bf16(pa3, vf1, o1, 0, 0, 0);
    }
    __builtin_amdgcn_s_setprio(0);
    cur = nxt;   // no bottom barrier, no lgkmcnt drain (3-buffer safety)
  }

  // epilogue: finish l over key-halves, normalize, store
  l_run += __shfl_xor(l_run, 32, 64);
  const float linv = 1.0f / l_run;
  const int b = bh / NHEADS, h = bh % NHEADS;
#pragma unroll
  for (int reg = 0; reg < 16; reg++) {
    const int qr = (reg & 3) + 8*(reg >> 2) + 4*hl;
    const float lr = __shfl(linv, qr, 64);
    const int t = qt*128 + w*32 + qr;
    unsigned short* dst = O2 + ((size_t)(b*SEQ + t))*DIMC + h*HDIM;
    dst[l31]      = f2bf(o0[reg] * lr);
    dst[32 + l31] = f2bf(o1[reg] * lr);
  }
}

// ---------------- proj GEMM (dbuf, BN=64, unchanged control): -> fp32 out ------
__global__ __launch_bounds__(256) void proj_gemm_kernel(
    const unsigned short* __restrict__ A,
    const unsigned short* __restrict__ W,
    const float* __restrict__ bias,
    float* __restrict__ out) {
  __shared__ unsigned short As[2][128*32];
  __shared__ unsigned short Bs[2][64*32];
  const int tid = threadIdx.x;
  const int w = tid >> 6, l = tid & 63;
  const int q4 = l >> 4, r15 = l & 15;
  const int m0 = blockIdx.y * 128;
  const int n0 = blockIdx.x * 64;

  f32x4 acc[2][4];
#pragma unroll
  for (int i = 0; i < 2; i++)
#pragma unroll
    for (int j = 0; j < 4; j++) acc[i][j] = f32x4{0.f, 0.f, 0.f, 0.f};

  const int arow = l >> 2;
  const int achk = l & 3;
  const unsigned short* Asrc = A + (size_t)(m0 + w*16 + arow) * 384 + achk * 8;
  const unsigned short* Wsrc = W + (size_t)(n0 + w*16 + arow) * 384 + achk * 8;

#pragma unroll
  for (int cc = 0; cc < 2; ++cc)
    async_load16(Asrc + cc*64*384, (char*)As[0] + cc*4096 + w*1024);
  async_load16(Wsrc, (char*)Bs[0] + w*1024);

  for (int kt = 0; kt < 12; ++kt) {
    const int buf = kt & 1;
    if (kt < 11) {
#pragma unroll
      for (int cc = 0; cc < 2; ++cc)
        async_load16(Asrc + (kt+1)*32 + cc*64*384, (char*)As[buf^1] + cc*4096 + w*1024);
      async_load16(Wsrc + (kt+1)*32, (char*)Bs[buf^1] + w*1024);
      asm volatile("s_waitcnt vmcnt(3)" ::: "memory");
    } else {
      asm volatile("s_waitcnt vmcnt(0)" ::: "memory");
    }
    __builtin_amdgcn_s_barrier();
    asm volatile("" ::: "memory");
    bf16x8 a[2], b[4];
#pragma unroll
    for (int mi = 0; mi < 2; mi++)
      a[mi] = *(const bf16x8*)(&As[buf][(w*32 + mi*16 + r15)*32 + q4*8]);
#pragma unroll
    for (int ni = 0; ni < 4; ni++)
      b[ni] = *(const bf16x8*)(&Bs[buf][(ni*16 + r15)*32 + q4*8]);
    __builtin_amdgcn_s_setprio(1);
#pragma unroll
    for (int mi = 0; mi < 2; mi++)
#pragma unroll
      for (int ni = 0; ni < 4; ni++)
        acc[mi][ni] = __builtin_amdgcn_mfma_f32_16x16x32_bf16(
            a[mi], b[ni], acc[mi][ni], 0, 0, 0);
    __builtin_amdgcn_s_setprio(0);
    asm volatile("s_waitcnt lgkmcnt(0)" ::: "memory");
    __builtin_amdgcn_s_barrier();
    asm volatile("" ::: "memory");
  }
#pragma unroll
  for (int ni = 0; ni < 4; ni++) {
    int ncol = n0 + ni*16 + r15;
    float bv = bias[ncol];
#pragma unroll
    for (int mi = 0; mi < 2; mi++) {
#pragma unroll
      for (int reg = 0; reg < 4; reg++) {
        int m = m0 + w*32 + mi*16 + 4*q4 + reg;
        out[(size_t)m * DIMC + ncol] = acc[mi][ni][reg] + bv;
      }
    }
  }
}

extern "C" void kernel_launch(void* const* d_in, const int* in_sizes, int n_in,
                              void* d_out, int out_size, void* d_ws, size_t ws_size,
                              hipStream_t stream) {
  const float* x      = (const float*)d_in[0];
  const float* qkv_w  = (const float*)d_in[1];
  const float* qkv_b  = (const float*)d_in[2];
  const float* proj_w = (const float*)d_in[3];
  const float* proj_b = (const float*)d_in[4];
  float* out = (float*)d_out;

  unsigned short* xbf   = (unsigned short*)d_ws;
  unsigned short* wqkv  = xbf   + (size_t)TOKENS * DIMC;
  unsigned short* wproj = wqkv  + (size_t)QKV_OUT * DIMC;
  unsigned short* Qb    = wproj + (size_t)DIMC * DIMC;
  unsigned short* Kb    = Qb    + (size_t)TOKENS * DIMC;
  unsigned short* Vtb   = Kb    + (size_t)TOKENS * DIMC;
  unsigned short* A2    = Vtb   + (size_t)TOKENS * DIMC;

  cast3_kernel<<<2048, 256, 0, stream>>>(x, qkv_w, proj_w, xbf, wqkv, wproj);
  qkv_gemm_kernel<<<dim3(9, 128), 256, 0, stream>>>(xbf, wqkv, qkv_b, Qb, Kb, Vtb);
  flash_kernel<<<768, 256, 0, stream>>>(Qb, Kb, Vtb, A2);
  proj_gemm_kernel<<<dim3(6, 128), 256, 0, stream>>>(A2, wproj, proj_b, out);
}

// Round 13
// 114.282 us; speedup vs baseline: 1.7417x; 1.0747x over previous
//
#include <hip/hip_runtime.h>

typedef __attribute__((ext_vector_type(8))) short bf16x8;
typedef __attribute__((ext_vector_type(4))) float f32x4;
typedef __attribute__((ext_vector_type(16))) float f32x16;
typedef __attribute__((ext_vector_type(4))) unsigned int u32x4;

#define DIMC 384
#define NHEADS 6
#define HDIM 64
#define BATCH 8
#define SEQ 2048
#define TOKENS (BATCH*SEQ)      /* 16384 */
#define QKV_OUT (3*DIMC)        /* 1152 */

__device__ __forceinline__ unsigned short f2bf(float f) {
  unsigned int u = __float_as_uint(f);
  u += 0x7fffu + ((u >> 16) & 1u);
  return (unsigned short)(u >> 16);
}

__device__ __forceinline__ unsigned int cvt_pk_bf16(float a, float b) {
  unsigned int r;
  asm volatile("v_cvt_pk_bf16_f32 %0, %1, %2" : "=v"(r) : "v"(a), "v"(b));
  return r;
}

__device__ __forceinline__ void async_load16(const void* g, void* l) {
  __builtin_amdgcn_global_load_lds(
      (const __attribute__((address_space(1))) unsigned int*)g,
      (__attribute__((address_space(3))) unsigned int*)l, 16, 0, 0);
}

// ---------------- merged cast fp32 -> bf16 (x, qkv_w, proj_w in one launch) ----------------
#define N4_X   (TOKENS*DIMC/4)
#define N4_W1  (QKV_OUT*DIMC/4)
#define N4_W2  (DIMC*DIMC/4)
__global__ void cast3_kernel(const float* __restrict__ x,
                             const float* __restrict__ w1,
                             const float* __restrict__ w2,
                             unsigned short* __restrict__ ox,
                             unsigned short* __restrict__ o1,
                             unsigned short* __restrict__ o2) {
  int i = blockIdx.x * blockDim.x + threadIdx.x;
  const int stride = gridDim.x * blockDim.x;
  for (; i < N4_X + N4_W1 + N4_W2; i += stride) {
    const float* src; unsigned short* dst; int j = i;
    if (j < N4_X)            { src = x;  dst = ox; }
    else if (j < N4_X+N4_W1) { j -= N4_X; src = w1; dst = o1; }
    else                     { j -= N4_X+N4_W1; src = w2; dst = o2; }
    float4 v = ((const float4*)src)[j];
    ushort4 o;
    o.x = f2bf(v.x); o.y = f2bf(v.y); o.z = f2bf(v.z); o.w = f2bf(v.w);
    ((ushort4*)dst)[j] = o;
  }
}

// ------- QKV GEMM (3-buffer, 1 barrier/iter, XCD row-panel locality) -------
// grid: 1152 blocks 1-D; each XCD owns 16 complete M-rows (all 9 N-cols) ->
// A row-panel (98 KB) is fetched from L3 once and L2-hits 8 more times.
__global__ __launch_bounds__(256) void qkv_gemm_kernel(
    const unsigned short* __restrict__ A,   // x bf16 [16384][384]
    const unsigned short* __restrict__ W,   // qkv_w bf16 [1152][384]
    const float* __restrict__ bias,         // [1152]
    unsigned short* __restrict__ Qb,        // [48][2048][64]
    unsigned short* __restrict__ Kb,        // [48][2048][64]
    unsigned short* __restrict__ Vtb) {     // [48][64][2048]  (transposed!)
  __shared__ unsigned short As[3][128*32];
  __shared__ unsigned short Bs[3][128*32];
  const int tid = threadIdx.x;
  const int w = tid >> 6, l = tid & 63;
  const int wm = w >> 1, wn = w & 1;
  const int q4 = l >> 4, r15 = l & 15;
  // XCD swizzle: 1152 blocks, 144/XCD = 16 rows x 9 cols, col fastest
  const int wg = blockIdx.x;
  const int logical = (wg & 7) * 144 + (wg >> 3);
  const int row = logical / 9, col = logical % 9;
  const int m0 = row * 128;
  const int n0 = col * 128;

  f32x4 acc[4][4];
#pragma unroll
  for (int i = 0; i < 4; i++)
#pragma unroll
    for (int j = 0; j < 4; j++) acc[i][j] = f32x4{0.f, 0.f, 0.f, 0.f};

  const int arow = l >> 2;            // 0..15 within wave
  const int achk = l & 3;
  const unsigned short* Asrc = A + (size_t)(m0 + w*16 + arow) * 384 + achk * 8;
  const unsigned short* Wsrc = W + (size_t)(n0 + w*16 + arow) * 384 + achk * 8;

  // prologue: stage tile 0 into buf 0
#pragma unroll
  for (int cc = 0; cc < 2; ++cc) {
    async_load16(Asrc + cc*64*384, (char*)&As[0][0] + cc*4096 + w*1024);
    async_load16(Wsrc + cc*64*384, (char*)&Bs[0][0] + cc*4096 + w*1024);
  }

  int cur = 0;
  for (int kt = 0; kt < 12; ++kt) {
    const int nxt = (cur == 2) ? 0 : cur + 1;
    if (kt < 11) {
#pragma unroll
      for (int cc = 0; cc < 2; ++cc) {
        async_load16(Asrc + (kt+1)*32 + cc*64*384, (char*)&As[0][0] + nxt*8192 + cc*4096 + w*1024);
        async_load16(Wsrc + (kt+1)*32 + cc*64*384, (char*)&Bs[0][0] + nxt*8192 + cc*4096 + w*1024);
      }
      asm volatile("s_waitcnt vmcnt(4)" ::: "memory");
    } else {
      asm volatile("s_waitcnt vmcnt(0)" ::: "memory");
    }
    __builtin_amdgcn_s_barrier();
    asm volatile("" ::: "memory");
    const unsigned short* asb = &As[0][0] + cur*4096;
    const unsigned short* bsb = &Bs[0][0] + cur*4096;
    bf16x8 a[4], b[4];
#pragma unroll
    for (int mi = 0; mi < 4; mi++)
      a[mi] = *(const bf16x8*)(asb + (wm*64 + mi*16 + r15)*32 + q4*8);
#pragma unroll
    for (int ni = 0; ni < 4; ni++)
      b[ni] = *(const bf16x8*)(bsb + (wn*64 + ni*16 + r15)*32 + q4*8);
    __builtin_amdgcn_s_setprio(1);
#pragma unroll
    for (int mi = 0; mi < 4; mi++)
#pragma unroll
      for (int ni = 0; ni < 4; ni++)
        acc[mi][ni] = __builtin_amdgcn_mfma_f32_16x16x32_bf16(
            a[mi], b[ni], acc[mi][ni], 0, 0, 0);
    __builtin_amdgcn_s_setprio(0);
    cur = nxt;
  }
  const int c3 = col / 3;
  const int nrel0 = (col % 3) * 128 + wn * 64;
  if (c3 == 2) {
#pragma unroll
    for (int ni = 0; ni < 4; ni++) {
      int ncol = nrel0 + ni*16 + r15;
      float bv = bias[n0 + wn*64 + ni*16 + r15];
      int h = ncol >> 6, d = ncol & 63;
#pragma unroll
      for (int mi = 0; mi < 4; mi++) {
        int m = m0 + wm*64 + mi*16 + 4*q4;
        int bb = m >> 11, t = m & 2047;
        ushort4 pk;
        pk.x = f2bf(acc[mi][ni][0] + bv);
        pk.y = f2bf(acc[mi][ni][1] + bv);
        pk.z = f2bf(acc[mi][ni][2] + bv);
        pk.w = f2bf(acc[mi][ni][3] + bv);
        *(ushort4*)(Vtb + ((size_t)(bb*NHEADS + h)*HDIM + d)*SEQ + t) = pk;
      }
    }
  } else {
    unsigned short* D = (c3 == 0) ? Qb : Kb;
    const float scale = (c3 == 0) ? 0.125f * 1.4426950408889634f : 1.0f;
#pragma unroll
    for (int ni = 0; ni < 4; ni++) {
      int ncol = nrel0 + ni*16 + r15;
      float bv = bias[n0 + wn*64 + ni*16 + r15];
      int h = ncol >> 6, d = ncol & 63;
#pragma unroll
      for (int mi = 0; mi < 4; mi++) {
#pragma unroll
        for (int reg = 0; reg < 4; reg++) {
          int m = m0 + wm*64 + mi*16 + 4*q4 + reg;
          int bb = m >> 11, t = m & 2047;
          float v = (acc[mi][ni][reg] + bv) * scale;
          D[((size_t)(bb*NHEADS + h)*SEQ + t)*HDIM + d] = f2bf(v);
        }
      }
    }
  }
}

// ---- flash attention: 3-buffer, 1 barrier/iter, PHASE-SPLIT softmax (R12, unchanged) ----
__global__ __launch_bounds__(256, 3) void flash_kernel(
    const unsigned short* __restrict__ Q, const unsigned short* __restrict__ K,
    const unsigned short* __restrict__ Vt, unsigned short* __restrict__ O2) {
  __shared__ unsigned short Ks[3][64*64];   // [key][dk], swizzled
  __shared__ unsigned short Vs[3][64*64];   // V^T [d][key], swizzled
  const int tid = threadIdx.x;
  const int w = tid >> 6, l = tid & 63;
  const int hl = l >> 5, l31 = l & 31, l7 = l & 7;
  // XCD-aware swizzle: 768 blocks, 96 per XCD -> each bh entirely on one XCD
  const int wg = blockIdx.x;
  const int logical = (wg & 7) * 96 + (wg >> 3);
  const int qt = logical & 15, bh = logical >> 4;
  const unsigned short* Qp = Q  + (size_t)bh * SEQ * HDIM;
  const unsigned short* Kp = K  + (size_t)bh * SEQ * HDIM;
  const unsigned short* Vp = Vt + (size_t)bh * HDIM * SEQ;

  // Q fragments (B-operand): qf[ks] = Q[qrow][ks*16 + hl*8 .. +7]
  const int qrow = qt*128 + w*32 + l31;
  bf16x8 qf[4];
#pragma unroll
  for (int ks = 0; ks < 4; ks++)
    qf[ks] = *(const bf16x8*)(Qp + (size_t)qrow*HDIM + ks*16 + hl*8);

  // staging: linear LDS dest; pre-swizzled global chunk = pos ^ (row&7) ^ octave(w)
  const int srow = w*8 + (l >> 3);
  const int sch  = l7 ^ (l >> 3) ^ w;
  const unsigned short* Ksrc = Kp + (size_t)srow*HDIM + sch*8;
  const unsigned short* Vsrc = Vp + (size_t)srow*SEQ  + sch*8;

  // ds_read byte offsets: row=l31, pos = (ks*2+hl) ^ (row&7) ^ ((row>>3)&3)
  const int swl = (l31 >> 3) & 3;
  int rdoff[4];
#pragma unroll
  for (int ks = 0; ks < 4; ks++)
    rdoff[ks] = l31*128 + (((ks*2 + hl) ^ l7 ^ swl) << 4);

  f32x16 o0 = {}, o1 = {};
  float l_run = 0.f;

  // prologue: stage tile 0 -> buf 0
  async_load16(Ksrc,           (char*)&Ks[0][0] + w*1024);
  async_load16(Ksrc + 32*HDIM, (char*)&Ks[0][0] + w*1024 + 4096);
  async_load16(Vsrc,           (char*)&Vs[0][0] + w*1024);
  async_load16(Vsrc + 32*SEQ,  (char*)&Vs[0][0] + w*1024 + 4096);

  int cur = 0;
  for (int kt = 0; kt < 32; ++kt) {
    const int nxt = (cur == 2) ? 0 : cur + 1;
    if (kt < 31) {
      const unsigned short* ks_ = Ksrc + (size_t)(kt+1)*64*HDIM;
      const unsigned short* vs_ = Vsrc + (size_t)(kt+1)*64;
      char* kd = (char*)&Ks[0][0] + nxt*8192 + w*1024;
      char* vd = (char*)&Vs[0][0] + nxt*8192 + w*1024;
      async_load16(ks_,           kd);
      async_load16(ks_ + 32*HDIM, kd + 4096);
      async_load16(vs_,           vd);
      async_load16(vs_ + 32*SEQ,  vd + 4096);
      asm volatile("s_waitcnt vmcnt(4)" ::: "memory");  // own tile-kt loads done
    } else {
      asm volatile("s_waitcnt vmcnt(0)" ::: "memory");
    }
    __builtin_amdgcn_s_barrier();       // single barrier: tile kt fully in LDS
    asm volatile("" ::: "memory");

    const char* ksb = (const char*)&Ks[0][0] + cur*8192;
    const char* vsb = (const char*)&Vs[0][0] + cur*8192;

    // ---- phase A: key-half 0 (keys 0-31): QK, exp2, pack; s + Y0 die before phase B ----
    bf16x8 pa0, pa1;
    float lsumA;
    {
      f32x16 s = {};
      __builtin_amdgcn_s_setprio(1);
#pragma unroll
      for (int ks = 0; ks < 4; ks++) {
        bf16x8 kf = *(const bf16x8*)(ksb + rdoff[ks]);
        s = __builtin_amdgcn_mfma_f32_32x32x16_bf16(kf, qf[ks], s, 0, 0, 0);
      }
      __builtin_amdgcn_s_setprio(0);
      unsigned int Y[4][2];
      float lsum = 0.f;
#pragma unroll
      for (int h = 0; h < 4; h++) {
        float a0 = __builtin_amdgcn_exp2f(s[4*h+0]);
        float a1 = __builtin_amdgcn_exp2f(s[4*h+1]);
        float a2 = __builtin_amdgcn_exp2f(s[4*h+2]);
        float a3 = __builtin_amdgcn_exp2f(s[4*h+3]);
        lsum += (a0+a1)+(a2+a3);
        Y[h][0] = cvt_pk_bf16(a0, a1);
        Y[h][1] = cvt_pk_bf16(a2, a3);
      }
      lsumA = lsum;
      {
        unsigned int x0 = Y[0][0], x1 = Y[0][1], y0 = Y[1][0], y1 = Y[1][1];
        asm volatile("v_permlane32_swap_b32 %0, %1" : "+v"(x0), "+v"(y0));
        asm volatile("v_permlane32_swap_b32 %0, %1" : "+v"(x1), "+v"(y1));
        u32x4 t; t[0] = x0; t[1] = x1; t[2] = y0; t[3] = y1;
        union { u32x4 u; bf16x8 b; } cvt; cvt.u = t;
        pa0 = cvt.b;
      }
      {
        unsigned int x0 = Y[2][0], x1 = Y[2][1], y0 = Y[3][0], y1 = Y[3][1];
        asm volatile("v_permlane32_swap_b32 %0, %1" : "+v"(x0), "+v"(y0));
        asm volatile("v_permlane32_swap_b32 %0, %1" : "+v"(x1), "+v"(y1));
        u32x4 t; t[0] = x0; t[1] = x1; t[2] = y0; t[3] = y1;
        union { u32x4 u; bf16x8 b; } cvt; cvt.u = t;
        pa1 = cvt.b;
      }
    }
    __builtin_amdgcn_sched_barrier(0);   // keep phase B from hoisting into A

    // ---- phase B: key-half 1 (keys 32-63): reuses the same accumulator registers ----
    bf16x8 pa2, pa3;
    float lsumB;
    {
      f32x16 s = {};
      __builtin_amdgcn_s_setprio(1);
#pragma unroll
      for (int ks = 0; ks < 4; ks++) {
        bf16x8 kf = *(const bf16x8*)(ksb + 4096 + rdoff[ks]);
        s = __builtin_amdgcn_mfma_f32_32x32x16_bf16(kf, qf[ks], s, 0, 0, 0);
      }
      __builtin_amdgcn_s_setprio(0);
      unsigned int Y[4][2];
      float lsum = 0.f;
#pragma unroll
      for (int h = 0; h < 4; h++) {
        float a0 = __builtin_amdgcn_exp2f(s[4*h+0]);
        float a1 = __builtin_amdgcn_exp2f(s[4*h+1]);
        float a2 = __builtin_amdgcn_exp2f(s[4*h+2]);
        float a3 = __builtin_amdgcn_exp2f(s[4*h+3]);
        lsum += (a0+a1)+(a2+a3);
        Y[h][0] = cvt_pk_bf16(a0, a1);
        Y[h][1] = cvt_pk_bf16(a2, a3);
      }
      lsumB = lsum;
      {
        unsigned int x0 = Y[0][0], x1 = Y[0][1], y0 = Y[1][0], y1 = Y[1][1];
        asm volatile("v_permlane32_swap_b32 %0, %1" : "+v"(x0), "+v"(y0));
        asm volatile("v_permlane32_swap_b32 %0, %1" : "+v"(x1), "+v"(y1));
        u32x4 t; t[0] = x0; t[1] = x1; t[2] = y0; t[3] = y1;
        union { u32x4 u; bf16x8 b; } cvt; cvt.u = t;
        pa2 = cvt.b;
      }
      {
        unsigned int x0 = Y[2][0], x1 = Y[2][1], y0 = Y[3][0], y1 = Y[3][1];
        asm volatile("v_permlane32_swap_b32 %0, %1" : "+v"(x0), "+v"(y0));
        asm volatile("v_permlane32_swap_b32 %0, %1" : "+v"(x1), "+v"(y1));
        u32x4 t; t[0] = x0; t[1] = x1; t[2] = y0; t[3] = y1;
        union { u32x4 u; bf16x8 b; } cvt; cvt.u = t;
        pa3 = cvt.b;
      }
    }
    l_run += lsumA + lsumB;
    __builtin_amdgcn_sched_barrier(0);   // keep PV reads from hoisting into B

    // ---- phase C: O += P @ V : D[m=q][n=d] ----
    __builtin_amdgcn_s_setprio(1);
    {
      bf16x8 vf0 = *(const bf16x8*)(vsb + rdoff[0]);
      bf16x8 vf1 = *(const bf16x8*)(vsb + 4096 + rdoff[0]);
      o0 = __builtin_amdgcn_mfma_f32_32x32x16_bf16(pa0, vf0, o0, 0, 0, 0);
      o1 = __builtin_amdgcn_mfma_f32_32x32x16_bf16(pa0, vf1, o1, 0, 0, 0);
      vf0 = *(const bf16x8*)(vsb + rdoff[1]);
      vf1 = *(const bf16x8*)(vsb + 4096 + rdoff[1]);
      o0 = __builtin_amdgcn_mfma_f32_32x32x16_bf16(pa1, vf0, o0, 0, 0, 0);
      o1 = __builtin_amdgcn_mfma_f32_32x32x16_bf16(pa1, vf1, o1, 0, 0, 0);
      vf0 = *(const bf16x8*)(vsb + rdoff[2]);
      vf1 = *(const bf16x8*)(vsb + 4096 + rdoff[2]);
      o0 = __builtin_amdgcn_mfma_f32_32x32x16_bf16(pa2, vf0, o0, 0, 0, 0);
      o1 = __builtin_amdgcn_mfma_f32_32x32x16_bf16(pa2, vf1, o1, 0, 0, 0);
      vf0 = *(const bf16x8*)(vsb + rdoff[3]);
      vf1 = *(const bf16x8*)(vsb + 4096 + rdoff[3]);
      o0 = __builtin_amdgcn_mfma_f32_32x32x16_bf16(pa3, vf0, o0, 0, 0, 0);
      o1 = __builtin_amdgcn_mfma_f32_32x32x16_bf16(pa3, vf1, o1, 0, 0, 0);
    }
    __builtin_amdgcn_s_setprio(0);
    cur = nxt;   // no bottom barrier, no lgkmcnt drain (3-buffer safety)
  }

  // epilogue: finish l over key-halves, normalize, store
  l_run += __shfl_xor(l_run, 32, 64);
  const float linv = 1.0f / l_run;
  const int b = bh / NHEADS, h = bh % NHEADS;
#pragma unroll
  for (int reg = 0; reg < 16; reg++) {
    const int qr = (reg & 3) + 8*(reg >> 2) + 4*hl;
    const float lr = __shfl(linv, qr, 64);
    const int t = qt*128 + w*32 + qr;
    unsigned short* dst = O2 + ((size_t)(b*SEQ + t))*DIMC + h*HDIM;
    dst[l31]      = f2bf(o0[reg] * lr);
    dst[32 + l31] = f2bf(o1[reg] * lr);
  }
}

// ------- proj GEMM (dbuf, BN=64, XCD row-panel locality): -> fp32 out -------
// grid: 768 blocks 1-D; each XCD owns 16 complete M-rows (all 6 N-cols).
__global__ __launch_bounds__(256) void proj_gemm_kernel(
    const unsigned short* __restrict__ A,
    const unsigned short* __restrict__ W,
    const float* __restrict__ bias,
    float* __restrict__ out) {
  __shared__ unsigned short As[2][128*32];
  __shared__ unsigned short Bs[2][64*32];
  const int tid = threadIdx.x;
  const int w = tid >> 6, l = tid & 63;
  const int q4 = l >> 4, r15 = l & 15;
  const int wg = blockIdx.x;
  const int logical = (wg & 7) * 96 + (wg >> 3);
  const int row = logical / 6, col = logical % 6;
  const int m0 = row * 128;
  const int n0 = col * 64;

  f32x4 acc[2][4];
#pragma unroll
  for (int i = 0; i < 2; i++)
#pragma unroll
    for (int j = 0; j < 4; j++) acc[i][j] = f32x4{0.f, 0.f, 0.f, 0.f};

  const int arow = l >> 2;
  const int achk = l & 3;
  const unsigned short* Asrc = A + (size_t)(m0 + w*16 + arow) * 384 + achk * 8;
  const unsigned short* Wsrc = W + (size_t)(n0 + w*16 + arow) * 384 + achk * 8;

#pragma unroll
  for (int cc = 0; cc < 2; ++cc)
    async_load16(Asrc + cc*64*384, (char*)As[0] + cc*4096 + w*1024);
  async_load16(Wsrc, (char*)Bs[0] + w*1024);

  for (int kt = 0; kt < 12; ++kt) {
    const int buf = kt & 1;
    if (kt < 11) {
#pragma unroll
      for (int cc = 0; cc < 2; ++cc)
        async_load16(Asrc + (kt+1)*32 + cc*64*384, (char*)As[buf^1] + cc*4096 + w*1024);
      async_load16(Wsrc + (kt+1)*32, (char*)Bs[buf^1] + w*1024);
      asm volatile("s_waitcnt vmcnt(3)" ::: "memory");
    } else {
      asm volatile("s_waitcnt vmcnt(0)" ::: "memory");
    }
    __builtin_amdgcn_s_barrier();
    asm volatile("" ::: "memory");
    bf16x8 a[2], b[4];
#pragma unroll
    for (int mi = 0; mi < 2; mi++)
      a[mi] = *(const bf16x8*)(&As[buf][(w*32 + mi*16 + r15)*32 + q4*8]);
#pragma unroll
    for (int ni = 0; ni < 4; ni++)
      b[ni] = *(const bf16x8*)(&Bs[buf][(ni*16 + r15)*32 + q4*8]);
    __builtin_amdgcn_s_setprio(1);
#pragma unroll
    for (int mi = 0; mi < 2; mi++)
#pragma unroll
      for (int ni = 0; ni < 4; ni++)
        acc[mi][ni] = __builtin_amdgcn_mfma_f32_16x16x32_bf16(
            a[mi], b[ni], acc[mi][ni], 0, 0, 0);
    __builtin_amdgcn_s_setprio(0);
    asm volatile("s_waitcnt lgkmcnt(0)" ::: "memory");
    __builtin_amdgcn_s_barrier();
    asm volatile("" ::: "memory");
  }
#pragma unroll
  for (int ni = 0; ni < 4; ni++) {
    int ncol = n0 + ni*16 + r15;
    float bv = bias[ncol];
#pragma unroll
    for (int mi = 0; mi < 2; mi++) {
#pragma unroll
      for (int reg = 0; reg < 4; reg++) {
        int m = m0 + w*32 + mi*16 + 4*q4 + reg;
        out[(size_t)m * DIMC + ncol] = acc[mi][ni][reg] + bv;
      }
    }
  }
}

extern "C" void kernel_launch(void* const* d_in, const int* in_sizes, int n_in,
                              void* d_out, int out_size, void* d_ws, size_t ws_size,
                              hipStream_t stream) {
  const float* x      = (const float*)d_in[0];
  const float* qkv_w  = (const float*)d_in[1];
  const float* qkv_b  = (const float*)d_in[2];
  const float* proj_w = (const float*)d_in[3];
  const float* proj_b = (const float*)d_in[4];
  float* out = (float*)d_out;

  unsigned short* xbf   = (unsigned short*)d_ws;
  unsigned short* wqkv  = xbf   + (size_t)TOKENS * DIMC;
  unsigned short* wproj = wqkv  + (size_t)QKV_OUT * DIMC;
  unsigned short* Qb    = wproj + (size_t)DIMC * DIMC;
  unsigned short* Kb    = Qb    + (size_t)TOKENS * DIMC;
  unsigned short* Vtb   = Kb    + (size_t)TOKENS * DIMC;
  unsigned short* A2    = Vtb   + (size_t)TOKENS * DIMC;

  cast3_kernel<<<2048, 256, 0, stream>>>(x, qkv_w, proj_w, xbf, wqkv, wproj);
  qkv_gemm_kernel<<<1152, 256, 0, stream>>>(xbf, wqkv, qkv_b, Qb, Kb, Vtb);
  flash_kernel<<<768, 256, 0, stream>>>(Qb, Kb, Vtb, A2);
  proj_gemm_kernel<<<768, 256, 0, stream>>>(A2, wproj, proj_b, out);
}